// Round 8
// baseline (77.779 us; speedup 1.0000x reference)
//
#include <hip/hip_runtime.h>
#include <math.h>

#define BB 32
#define SS 2048
#define HH 1024
#define RR 64
#define H4 (HH/4)
#define SPIN_CAP 4000000

// flag: 0 = int32, 1 = uint8(bool), 2 = float32
__device__ __forceinline__ bool read_mask(const void* m, int flag, int i) {
    if (flag == 1) return ((const unsigned char*)m)[i] != 0;
    if (flag == 2) return ((const float*)m)[i] != 0.0f;
    return ((const int*)m)[i] != 0;
}

__device__ __forceinline__ float dot4(float4 a, float4 b) {
    return a.x * b.x + a.y * b.y + a.z * b.z + a.w * b.w;
}

// ---------------- single fused kernel ----------------
// grid = 1024, block = 256, blk = q*32 + b (q in [0,32)); each block owns
// rubrics r = 2q, 2q+1 of batch b. All of batch b's blocks -> XCD b%8.
// __launch_bounds__(256,4): VGPR cap 128 (no spills, unlike R5's 64-cap),
// grid 1024 = 4/CU * 256 CU -> ALL blocks co-resident by occupancy, so the
// vcnt wait is deadlock-free with no dispatch-order assumption and NO
// fallback path (R5's register-bloat killer).
//   q < 16  : producer duty first — answer pool + v[b, q*64 .. q*64+64)
//             (relaxed-agent stores + vmcnt(0) + device-scope vcnt[b]++).
//   all     : pool both rubric spans into REGISTERS (no u materialization,
//             R7's lesson), s_sleep-throttled wait for vcnt[b]==16, dot,
//             fence-free softmax handoff (R3-proven).
__global__ __launch_bounds__(256, 4)
void fused_k(const float4* __restrict__ seq,
             const float4* __restrict__ W4,
             const int* __restrict__ rspan,
             const int* __restrict__ aspan,
             const void* __restrict__ mask,
             const float* __restrict__ bias,
             float* __restrict__ v,
             unsigned int* __restrict__ vcnt,
             unsigned int* __restrict__ cnt,
             float* __restrict__ scores,
             float* __restrict__ out) {
    int blk = blockIdx.x, t = threadIdx.x;
    int b = blk & (BB - 1), q = blk >> 5;
    int wave = t >> 6, lane = t & 63;
    int idx0 = b * RR + 2 * q;
    int idx1 = idx0 + 1;

    // --- mask dtype classify (2 KB L2-resident scan; ~free) ---
    // uint8 bool => nonzero at i%4==1; f32 => nonzero only at i%4==3;
    // int32 => nonzero only at i%4==0.
    __shared__ int c1s, c3s;
    if (t == 0) { c1s = 0; c3s = 0; }
    __syncthreads();
    {
        const unsigned char* mb = (const unsigned char*)mask;
        int c1 = 0, c3 = 0;
        for (int i = t; i < BB * RR; i += 256) {
            if (mb[i]) {
                int p = i & 3;
                if (p == 1) c1 = 1;
                else if (p == 3) c3 = 1;
            }
        }
        if (c1) atomicOr(&c1s, 1);
        if (c3) atomicOr(&c3s, 1);
    }
    __syncthreads();
    int flag = c1s ? 1 : (c3s ? 2 : 0);
    bool mk0 = read_mask(mask, flag, idx0);
    bool mk1 = read_mask(mask, flag, idx1);

    const float4* base = seq + (size_t)b * SS * H4 + t;

    // ---------------- producer duty (q < 16) ----------------
    if (q < 16) {
        int s0 = aspan[2 * b], s1 = aspan[2 * b + 1];
        int alen = s1 - s0; if (alen < 1) alen = 1;
        float4 a = make_float4(0.f, 0.f, 0.f, 0.f);
        for (int s = s0; s < s1; ++s) {
            float4 x = base[(size_t)s * H4];
            a.x += x.x; a.y += x.y; a.z += x.z; a.w += x.w;
        }
        float inv = 1.0f / (float)alen;
        a.x *= inv; a.y *= inv; a.z *= inv; a.w *= inv;
        __shared__ float4 aS[256];
        aS[t] = a;
        __syncthreads();
        float4 al0 = aS[0 * 64 + lane], al1 = aS[1 * 64 + lane],
               al2 = aS[2 * 64 + lane], al3 = aS[3 * 64 + lane];
        int hbase = q * 64 + wave * 16;
        for (int rr = 0; rr < 16; ++rr) {
            int h = hbase + rr;
            const float4* Wrow = W4 + (size_t)h * H4;
            float p = dot4(Wrow[0 * 64 + lane], al0)
                    + dot4(Wrow[1 * 64 + lane], al1)
                    + dot4(Wrow[2 * 64 + lane], al2)
                    + dot4(Wrow[3 * 64 + lane], al3);
            for (int off = 32; off; off >>= 1) p += __shfl_down(p, off);
            if (lane == 0)
                __hip_atomic_store(&v[b * HH + h], p, __ATOMIC_RELAXED,
                                   __HIP_MEMORY_SCOPE_AGENT);
        }
        asm volatile("s_waitcnt vmcnt(0)" ::: "memory"); // v @ coherence point
        __syncthreads();                                 // all 4 waves drained
        if (t == 0) atomicAdd(&vcnt[b], 1u);             // device-scope signal
    }

    // ------- rubric span pooling into registers (bulk HBM phase) -------
    float4 u0 = make_float4(0.f, 0.f, 0.f, 0.f);
    float4 u1 = make_float4(0.f, 0.f, 0.f, 0.f);
    if (mk0) {
        int s0 = rspan[2 * idx0], s1 = rspan[2 * idx0 + 1];
        int len = s1 - s0; if (len < 1) len = 1;
        for (int s = s0; s < s1; ++s) {
            float4 x = base[(size_t)s * H4];
            u0.x += x.x; u0.y += x.y; u0.z += x.z; u0.w += x.w;
        }
        float inv = 1.0f / (float)len;
        u0.x *= inv; u0.y *= inv; u0.z *= inv; u0.w *= inv;
    }
    if (mk1) {
        int s0 = rspan[2 * idx1], s1 = rspan[2 * idx1 + 1];
        int len = s1 - s0; if (len < 1) len = 1;
        for (int s = s0; s < s1; ++s) {
            float4 x = base[(size_t)s * H4];
            u1.x += x.x; u1.y += x.y; u1.z += x.z; u1.w += x.w;
        }
        float inv = 1.0f / (float)len;
        u1.x *= inv; u1.y *= inv; u1.z *= inv; u1.w *= inv;
    }

    // ------- wait for v[b] (throttled single-thread poll) -------
    __shared__ int vready;
    if (t == 0) {
        unsigned c = __hip_atomic_load(&vcnt[b], __ATOMIC_RELAXED,
                                       __HIP_MEMORY_SCOPE_AGENT);
        long it = 0;
        while (c < 16u && it < SPIN_CAP) {
            __builtin_amdgcn_s_sleep(16);      // ~1K cyc between polls
            c = __hip_atomic_load(&vcnt[b], __ATOMIC_RELAXED,
                                  __HIP_MEMORY_SCOPE_AGENT);
            ++it;
        }
        vready = 1;
    }
    __syncthreads();

    // ------- dot + block reduce -------
    float4 vv;
    vv.x = __hip_atomic_load(&v[b * HH + 4 * t + 0], __ATOMIC_RELAXED,
                             __HIP_MEMORY_SCOPE_AGENT);
    vv.y = __hip_atomic_load(&v[b * HH + 4 * t + 1], __ATOMIC_RELAXED,
                             __HIP_MEMORY_SCOPE_AGENT);
    vv.z = __hip_atomic_load(&v[b * HH + 4 * t + 2], __ATOMIC_RELAXED,
                             __HIP_MEMORY_SCOPE_AGENT);
    vv.w = __hip_atomic_load(&v[b * HH + 4 * t + 3], __ATOMIC_RELAXED,
                             __HIP_MEMORY_SCOPE_AGENT);
    float p0 = dot4(u0, vv), p1 = dot4(u1, vv);
    for (int off = 32; off; off >>= 1) {
        p0 += __shfl_down(p0, off);
        p1 += __shfl_down(p1, off);
    }
    __shared__ float red0[4], red1[4];
    __shared__ int lastB;
    if (lane == 0) { red0[wave] = p0; red1[wave] = p1; }
    __syncthreads();
    if (t == 0) {
        float s0s = red0[0] + red0[1] + red0[2] + red0[3];
        float s1s = red1[0] + red1[1] + red1[2] + red1[3];
        float bv = bias[0];
        float val0 = mk0 ? (s0s + bv) : -INFINITY;   // u already /len
        float val1 = mk1 ? (s1s + bv) : -INFINITY;
        __hip_atomic_store(&scores[idx0], val0, __ATOMIC_RELAXED,
                           __HIP_MEMORY_SCOPE_AGENT);
        __hip_atomic_store(&scores[idx1], val1, __ATOMIC_RELAXED,
                           __HIP_MEMORY_SCOPE_AGENT);
        asm volatile("s_waitcnt vmcnt(0)" ::: "memory"); // scores @ coherence pt
        unsigned old = atomicAdd(&cnt[b], 2u);           // relaxed, device
        asm volatile("" ::: "memory");
        lastB = (old == RR - 2);
    }
    __syncthreads();
    if (lastB && t < RR) {
        float x = __hip_atomic_load(&scores[b * RR + t], __ATOMIC_RELAXED,
                                    __HIP_MEMORY_SCOPE_AGENT);
        float m = x;
        for (int off = 32; off; off >>= 1) m = fmaxf(m, __shfl_xor(m, off));
        float e = expf(x - m);              // -inf lanes -> 0
        float s = e;
        for (int off = 32; off; off >>= 1) s += __shfl_xor(s, off);
        out[b * RR + t] = e / s;
    }
}

extern "C" void kernel_launch(void* const* d_in, const int* in_sizes, int n_in,
                              void* d_out, int out_size, void* d_ws, size_t ws_size,
                              hipStream_t stream) {
    const float* seq  = (const float*)d_in[0];
    const float* Wm   = (const float*)d_in[1];
    const float* bias = (const float*)d_in[2];
    const int*   rspan = (const int*)d_in[3];
    const int*   aspan = (const int*)d_in[4];
    const void*  mask  = d_in[5];

    char* ws = (char*)d_ws;
    unsigned int* vcnt   = (unsigned int*)ws;               // 32 u32 @0
    unsigned int* cnt    = (unsigned int*)(ws + 128);       // 32 u32 @128
    float*        scores = (float*)(ws + 4096);             // 2048 f
    float*        v      = (float*)(ws + 16384);            // 32*1024 f

    hipMemsetAsync(ws, 0, 512, stream);                     // zero vcnt+cnt
    fused_k<<<1024, 256, 0, stream>>>(
        (const float4*)seq, (const float4*)Wm, rspan, aspan, mask, bias,
        v, vcnt, cnt, scores, (float*)d_out);
}

// Round 9
// 45.162 us; speedup vs baseline: 1.7222x; 1.7222x over previous
//
#include <hip/hip_runtime.h>
#include <math.h>

#define BB 32
#define SS 2048
#define HH 1024
#define RR 64
#define H4 (HH/4)

// flag: 0 = int32, 1 = uint8(bool), 2 = float32
__device__ __forceinline__ bool read_mask(const void* m, int flag, int i) {
    if (flag == 1) return ((const unsigned char*)m)[i] != 0;
    if (flag == 2) return ((const float*)m)[i] != 0.0f;
    return ((const int*)m)[i] != 0;
}

__device__ __forceinline__ float dot4(float4 a, float4 b) {
    return a.x * b.x + a.y * b.y + a.z * b.z + a.w * b.w;
}

// ---------------- K1: answer pool + bilinear matvec (fused) ----------------
// grid = 512, block = 256. b = blk&31, hg = blk>>5 (all 16 blocks of batch b
// on XCD b%8). Each block recomputes a[b] into LDS, then computes
// v[b, hg*64 .. hg*64+64) with coalesced W reads. Block 0 classifies the
// rubric_mask storage dtype and zeroes K2's per-batch softmax counters.
__global__ void pool_matvec_k(const float4* __restrict__ seq,
                              const float4* __restrict__ W4,
                              const int* __restrict__ aspan,
                              const unsigned char* __restrict__ mask,
                              float* __restrict__ v,
                              int* __restrict__ flag,
                              unsigned int* __restrict__ cnt) {
    int blk = blockIdx.x, t = threadIdx.x;
    int b = blk & (BB - 1), hg = blk >> 5;

    int s0 = aspan[2 * b], s1 = aspan[2 * b + 1];
    int len = s1 - s0; if (len < 1) len = 1;
    float4 acc = make_float4(0.f, 0.f, 0.f, 0.f);
    const float4* base = seq + (size_t)b * SS * H4 + t;
    for (int s = s0; s < s1; ++s) {
        float4 x = base[(size_t)s * H4];
        acc.x += x.x; acc.y += x.y; acc.z += x.z; acc.w += x.w;
    }
    float inv = 1.0f / (float)len;
    acc.x *= inv; acc.y *= inv; acc.z *= inv; acc.w *= inv;

    __shared__ float4 aS[256];
    aS[t] = acc;
    __syncthreads();

    int wave = t >> 6, lane = t & 63;
    float4 al0 = aS[0 * 64 + lane], al1 = aS[1 * 64 + lane],
           al2 = aS[2 * 64 + lane], al3 = aS[3 * 64 + lane];
    int hbase = hg * 64 + wave * 16;
    for (int r = 0; r < 16; ++r) {
        int h = hbase + r;
        const float4* Wrow = W4 + (size_t)h * H4;
        float p = dot4(Wrow[0 * 64 + lane], al0)
                + dot4(Wrow[1 * 64 + lane], al1)
                + dot4(Wrow[2 * 64 + lane], al2)
                + dot4(Wrow[3 * 64 + lane], al3);
        for (int off = 32; off; off >>= 1) p += __shfl_down(p, off);
        if (lane == 0) v[b * HH + h] = p;
    }

    if (blk == 0) {
        // uint8 bool => nonzero at i%4==1; f32 => nonzero only at i%4==3;
        // int32 => nonzero only at i%4==0.
        __shared__ int c1s, c3s;
        if (t == 0) { c1s = 0; c3s = 0; }
        __syncthreads();
        int c1 = 0, c3 = 0;
        for (int i = t; i < BB * RR; i += 256) {
            if (mask[i]) {
                int p = i & 3;
                if (p == 1) c1 = 1;
                else if (p == 3) c3 = 1;
            }
        }
        if (c1) atomicOr(&c1s, 1);
        if (c3) atomicOr(&c3s, 1);
        __syncthreads();
        if (t == 0) *flag = c1s ? 1 : (c3s ? 2 : 0);
        if (t < BB) cnt[t] = 0u;    // re-zero every launch (graph replay safe)
    }
}

// ---------------- K2: rubric scores (2 per block) + fused softmax ----------
// grid = 1024, block = 256, blk = q*32 + b: block owns rubrics 2q, 2q+1 of
// batch b (batch b's 32 blocks -> XCD b%8, span-row L2 reuse).
// The two span loops are INTERLEAVED in one loop: 2 independent load chains
// per thread (2x memory-level parallelism in the latency-critical HBM phase),
// and all per-block fixed costs (flag/mask loads, 4 KB v4[b] load, reduce,
// handoff atomics) are paid once per TWO rubrics (R6 paid them per rubric).
// Fence-free cross-XCD softmax handoff (R3-proven): relaxed agent-scope score
// stores, s_waitcnt vmcnt(0), relaxed device-scope cnt[b] += 2; the last
// arriver (old == 62) runs the 64-wide softmax. No acquire/release.
__global__ void rubric2_scores_softmax_k(const float4* __restrict__ seq,
                                         const float4* __restrict__ v4,
                                         const int* __restrict__ rspan,
                                         const void* __restrict__ mask,
                                         const int* __restrict__ flagp,
                                         const float* __restrict__ bias,
                                         float* __restrict__ scores,
                                         unsigned int* __restrict__ cnt,
                                         float* __restrict__ out) {
    int blk = blockIdx.x, t = threadIdx.x;
    int b = blk & (BB - 1), q = blk >> 5;
    int idx0 = b * RR + 2 * q;
    int idx1 = idx0 + 1;
    int wave = t >> 6, lane = t & 63;

    int flag = *flagp;
    bool mk0 = read_mask(mask, flag, idx0);
    bool mk1 = read_mask(mask, flag, idx1);

    int s00 = 0, n0 = 0, len0 = 1;
    int s10 = 0, n1 = 0, len1 = 1;
    if (mk0) {
        s00 = rspan[2 * idx0];
        int e = rspan[2 * idx0 + 1];
        n0 = e - s00; len0 = n0 < 1 ? 1 : n0;
    }
    if (mk1) {
        s10 = rspan[2 * idx1];
        int e = rspan[2 * idx1 + 1];
        n1 = e - s10; len1 = n1 < 1 ? 1 : n1;
    }

    float4 vv = v4[b * H4 + t];
    const float4* base = seq + (size_t)b * SS * H4 + t;
    float p0 = 0.f, p1 = 0.f;
    int nmax = n0 > n1 ? n0 : n1;
    for (int i = 0; i < nmax; ++i) {            // wave-uniform predicates
        if (i < n0) p0 += dot4(base[(size_t)(s00 + i) * H4], vv);
        if (i < n1) p1 += dot4(base[(size_t)(s10 + i) * H4], vv);
    }

    for (int off = 32; off; off >>= 1) {
        p0 += __shfl_down(p0, off);
        p1 += __shfl_down(p1, off);
    }
    __shared__ float red0[4], red1[4];
    __shared__ int lastB;
    if (lane == 0) { red0[wave] = p0; red1[wave] = p1; }
    __syncthreads();
    if (t == 0) {
        float sA = red0[0] + red0[1] + red0[2] + red0[3];
        float sB = red1[0] + red1[1] + red1[2] + red1[3];
        float bv = bias[0];
        float val0 = mk0 ? (sA / (float)len0 + bv) : -INFINITY;
        float val1 = mk1 ? (sB / (float)len1 + bv) : -INFINITY;
        __hip_atomic_store(&scores[idx0], val0, __ATOMIC_RELAXED,
                           __HIP_MEMORY_SCOPE_AGENT);
        __hip_atomic_store(&scores[idx1], val1, __ATOMIC_RELAXED,
                           __HIP_MEMORY_SCOPE_AGENT);
        asm volatile("s_waitcnt vmcnt(0)" ::: "memory");  // scores @ coherence
        unsigned old = atomicAdd(&cnt[b], 2u);            // relaxed, device
        asm volatile("" ::: "memory");
        lastB = (old == RR - 2);
    }
    __syncthreads();
    if (lastB && t < RR) {
        float x = __hip_atomic_load(&scores[b * RR + t], __ATOMIC_RELAXED,
                                    __HIP_MEMORY_SCOPE_AGENT);
        float m = x;
        for (int off = 32; off; off >>= 1) m = fmaxf(m, __shfl_xor(m, off));
        float e = expf(x - m);              // -inf lanes -> 0
        float s = e;
        for (int off = 32; off; off >>= 1) s += __shfl_xor(s, off);
        out[b * RR + t] = e / s;
    }
}

extern "C" void kernel_launch(void* const* d_in, const int* in_sizes, int n_in,
                              void* d_out, int out_size, void* d_ws, size_t ws_size,
                              hipStream_t stream) {
    const float* seq  = (const float*)d_in[0];
    const float* Wm   = (const float*)d_in[1];
    const float* bias = (const float*)d_in[2];
    const int*   rspan = (const int*)d_in[3];
    const int*   aspan = (const int*)d_in[4];
    const void*  mask  = d_in[5];

    char* ws = (char*)d_ws;
    int*          flag   = (int*)ws;                        // @0
    unsigned int* cnt    = (unsigned int*)(ws + 256);       // 32 u32
    float*        scores = (float*)(ws + 4096);             // 2048 f
    float*        v      = (float*)(ws + 16384);            // 32*1024 f

    pool_matvec_k<<<BB * 16, 256, 0, stream>>>(
        (const float4*)seq, (const float4*)Wm, aspan,
        (const unsigned char*)mask, v, flag, cnt);
    rubric2_scores_softmax_k<<<1024, 256, 0, stream>>>(
        (const float4*)seq, (const float4*)v, rspan, mask, flag, bias,
        scores, cnt, (float*)d_out);
}

// Round 10
// 40.650 us; speedup vs baseline: 1.9134x; 1.1110x over previous
//
#include <hip/hip_runtime.h>
#include <math.h>

#define BB 32
#define SS 2048
#define HH 1024
#define RR 64
#define H4 (HH/4)

// flag: 0 = int32, 1 = uint8(bool), 2 = float32
__device__ __forceinline__ bool read_mask(const void* m, int flag, int i) {
    if (flag == 1) return ((const unsigned char*)m)[i] != 0;
    if (flag == 2) return ((const float*)m)[i] != 0.0f;
    return ((const int*)m)[i] != 0;
}

__device__ __forceinline__ float dot4(float4 a, float4 b) {
    return a.x * b.x + a.y * b.y + a.z * b.z + a.w * b.w;
}

// ---------------- K1: answer pool + bilinear matvec (fused) ----------------
// grid = 512, block = 256. b = blk&31, hg = blk>>5 (all 16 blocks of batch b
// on XCD b%8). Each block recomputes a[b] into LDS, then computes
// v[b, hg*64 .. hg*64+64) with coalesced W reads. Block 0 classifies the
// rubric_mask storage dtype and zeroes K2's per-batch softmax counters.
__global__ void pool_matvec_k(const float4* __restrict__ seq,
                              const float4* __restrict__ W4,
                              const int* __restrict__ aspan,
                              const unsigned char* __restrict__ mask,
                              float* __restrict__ v,
                              int* __restrict__ flag,
                              unsigned int* __restrict__ cnt) {
    int blk = blockIdx.x, t = threadIdx.x;
    int b = blk & (BB - 1), hg = blk >> 5;

    int s0 = aspan[2 * b], s1 = aspan[2 * b + 1];
    int len = s1 - s0; if (len < 1) len = 1;
    float4 acc = make_float4(0.f, 0.f, 0.f, 0.f);
    const float4* base = seq + (size_t)b * SS * H4 + t;
    for (int s = s0; s < s1; ++s) {
        float4 x = base[(size_t)s * H4];
        acc.x += x.x; acc.y += x.y; acc.z += x.z; acc.w += x.w;
    }
    float inv = 1.0f / (float)len;
    acc.x *= inv; acc.y *= inv; acc.z *= inv; acc.w *= inv;

    __shared__ float4 aS[256];
    aS[t] = acc;
    __syncthreads();

    int wave = t >> 6, lane = t & 63;
    float4 al0 = aS[0 * 64 + lane], al1 = aS[1 * 64 + lane],
           al2 = aS[2 * 64 + lane], al3 = aS[3 * 64 + lane];
    int hbase = hg * 64 + wave * 16;
    for (int r = 0; r < 16; ++r) {
        int h = hbase + r;
        const float4* Wrow = W4 + (size_t)h * H4;
        float p = dot4(Wrow[0 * 64 + lane], al0)
                + dot4(Wrow[1 * 64 + lane], al1)
                + dot4(Wrow[2 * 64 + lane], al2)
                + dot4(Wrow[3 * 64 + lane], al3);
        for (int off = 32; off; off >>= 1) p += __shfl_down(p, off);
        if (lane == 0) v[b * HH + h] = p;
    }

    if (blk == 0) {
        // uint8 bool => nonzero at i%4==1; f32 => nonzero only at i%4==3;
        // int32 => nonzero only at i%4==0.
        __shared__ int c1s, c3s;
        if (t == 0) { c1s = 0; c3s = 0; }
        __syncthreads();
        int c1 = 0, c3 = 0;
        for (int i = t; i < BB * RR; i += 256) {
            if (mask[i]) {
                int p = i & 3;
                if (p == 1) c1 = 1;
                else if (p == 3) c3 = 1;
            }
        }
        if (c1) atomicOr(&c1s, 1);
        if (c3) atomicOr(&c3s, 1);
        __syncthreads();
        if (t == 0) *flag = c1s ? 1 : (c3s ? 2 : 0);
        if (t < BB) cnt[t] = 0u;    // re-zero every launch (graph replay safe)
    }
}

// ---------------- K2: rubric scores + fused softmax (R6 + micro-opts) ------
// grid = B*R = 2048, block = 256, blk = r*32 + b (batch b's 64 blocks on XCD
// b%8, span-row L2 reuse). Micro-opts vs R6:
//  (1) rspan / v4 loads hoisted ABOVE the mask branch — spans are valid for
//      all (b,r) in this problem (mask applied after generation), so the
//      dependent chain flag->mask->rspan becomes three concurrent loads.
//  (2) span loop unrolled x2 with dual accumulators — two independent FMA
//      chains per thread double outstanding loads in the HBM-latency phase.
// Fence-free cross-XCD softmax handoff (R3-proven): relaxed agent-scope score
// store, s_waitcnt vmcnt(0), relaxed device-scope cnt[b]++; last arriver
// (old == 63) runs the 64-wide softmax. No acquire/release -> no cache walks.
__global__ void rubric_scores_softmax_k(const float4* __restrict__ seq,
                                        const float4* __restrict__ v4,
                                        const int* __restrict__ rspan,
                                        const void* __restrict__ mask,
                                        const int* __restrict__ flagp,
                                        const float* __restrict__ bias,
                                        float* __restrict__ scores,
                                        unsigned int* __restrict__ cnt,
                                        float* __restrict__ out) {
    int blk = blockIdx.x;
    int b = blk & (BB - 1);
    int r = blk >> 5;
    int t = threadIdx.x;
    int idx = b * RR + r;

    // independent loads, all issued up front
    int s0 = rspan[idx * 2], s1 = rspan[idx * 2 + 1];
    float4 vv = v4[b * H4 + t];
    int flag = *flagp;
    bool mk = read_mask(mask, flag, idx);

    int n = s1 - s0;
    int len = n < 1 ? 1 : n;

    float p = 0.f;
    if (mk) {
        const float4* base = seq + (size_t)b * SS * H4 + t;
        float pA = 0.f, pB = 0.f;
        int s = s0;
        for (; s + 1 < s1; s += 2) {
            pA += dot4(base[(size_t)s * H4], vv);
            pB += dot4(base[(size_t)(s + 1) * H4], vv);
        }
        if (s < s1) pA += dot4(base[(size_t)s * H4], vv);
        p = pA + pB;
    }
    __shared__ float red[4];
    __shared__ int lastB;
    int wave = t >> 6, lane = t & 63;
    for (int off = 32; off; off >>= 1) p += __shfl_down(p, off);
    if (lane == 0) red[wave] = p;
    __syncthreads();
    if (t == 0) {
        float s = red[0] + red[1] + red[2] + red[3];
        float val = mk ? (s / (float)len + bias[0]) : -INFINITY;
        __hip_atomic_store(&scores[idx], val, __ATOMIC_RELAXED,
                           __HIP_MEMORY_SCOPE_AGENT);
        asm volatile("s_waitcnt vmcnt(0)" ::: "memory");  // score @ coherence pt
        unsigned old = atomicAdd(&cnt[b], 1u);            // relaxed, device
        asm volatile("" ::: "memory");
        lastB = (old == RR - 1);
    }
    __syncthreads();
    if (lastB && t < RR) {
        float x = __hip_atomic_load(&scores[b * RR + t], __ATOMIC_RELAXED,
                                    __HIP_MEMORY_SCOPE_AGENT);
        float m = x;
        for (int off = 32; off; off >>= 1) m = fmaxf(m, __shfl_xor(m, off));
        float e = expf(x - m);              // -inf lanes -> 0
        float s = e;
        for (int off = 32; off; off >>= 1) s += __shfl_xor(s, off);
        out[b * RR + t] = e / s;
    }
}

extern "C" void kernel_launch(void* const* d_in, const int* in_sizes, int n_in,
                              void* d_out, int out_size, void* d_ws, size_t ws_size,
                              hipStream_t stream) {
    const float* seq  = (const float*)d_in[0];
    const float* Wm   = (const float*)d_in[1];
    const float* bias = (const float*)d_in[2];
    const int*   rspan = (const int*)d_in[3];
    const int*   aspan = (const int*)d_in[4];
    const void*  mask  = d_in[5];

    char* ws = (char*)d_ws;
    int*          flag   = (int*)ws;                        // @0
    unsigned int* cnt    = (unsigned int*)(ws + 256);       // 32 u32
    float*        scores = (float*)(ws + 4096);             // 2048 f
    float*        v      = (float*)(ws + 16384);            // 32*1024 f

    pool_matvec_k<<<BB * 16, 256, 0, stream>>>(
        (const float4*)seq, (const float4*)Wm, aspan,
        (const unsigned char*)mask, v, flag, cnt);
    rubric_scores_softmax_k<<<BB * RR, 256, 0, stream>>>(
        (const float4*)seq, (const float4*)v, rspan, mask, flag, bias,
        scores, cnt, (float*)d_out);
}